// Round 10
// baseline (149.494 us; speedup 1.0000x reference)
//
#include <hip/hip_runtime.h>

typedef __attribute__((ext_vector_type(4)))  float  f32x4;
typedef __attribute__((ext_vector_type(16))) float  f32x16;
typedef __attribute__((ext_vector_type(8)))  __bf16 bf16x8;
typedef __attribute__((ext_vector_type(2)))  unsigned u32x2;

constexpr int Bv = 8, Nv = 2048, Hv = 4, Dv = 64, OUTv = 256, HD = 256;
constexpr int BH = Bv * Hv;                      // 32
constexpr size_t PH = (size_t)BH * Nv * Dv;      // elements per [bh][n][d] buffer

#if __has_builtin(__builtin_amdgcn_exp2f)
#define EXP2(x) __builtin_amdgcn_exp2f(x)
#else
#define EXP2(x) exp2f(x)
#endif

// native bf16 conversions -> v_cvt_pk_bf16_f32 (RNE)
__device__ __forceinline__ unsigned short f2bf(float f) {
    union { __bf16 h; unsigned short u; } r;
    r.h = (__bf16)f;
    return r.u;
}

__device__ __forceinline__ unsigned pk_bf16(float a, float b) {
    union { __bf16 h[2]; unsigned u; } r;
    r.h[0] = (__bf16)a; r.h[1] = (__bf16)b;
    return r.u;
}

__device__ __forceinline__ uint4 pack8(const float* f) {
    uint4 u;
    u.x = pk_bf16(f[0], f[1]);
    u.y = pk_bf16(f[2], f[3]);
    u.z = pk_bf16(f[4], f[5]);
    u.w = pk_bf16(f[6], f[7]);
    return u;
}

__device__ __forceinline__ void swap32(unsigned a, unsigned b, unsigned& lo, unsigned& hi) {
#if __has_builtin(__builtin_amdgcn_permlane32_swap)
    u32x2 r = __builtin_amdgcn_permlane32_swap(a, b, false, false);
    lo = r.x; hi = r.y;
#else
    const int ishi = (threadIdx.x & 63) >> 5;
    unsigned pa = __shfl_xor(a, 32, 64), pb = __shfl_xor(b, 32, 64);
    lo = ishi ? pb : a;
    hi = ishi ? b : pa;
#endif
}

#define GLOBAL_AS __attribute__((address_space(1)))
#define LDS_AS    __attribute__((address_space(3)))

// ---------------------------------------------------------------------------
// Kernel 0: weight preconversion via coalesced LDS transpose.
// Blocks 0..11:  (m,h) -> Wt3[m][h][e][d] = W_m[h][d][e] bf16 (64x64 tile)
// Blocks 12..27: (er,cr) -> Wpt[e][c] = Wp[c][e] bf16 (64x64 tiles of 256x256)
// Rotate-swizzled LDS tile: elem (r,c) at tile[r*64 + ((c+r)&63)] -> 2-way max.
// ---------------------------------------------------------------------------
__global__ __launch_bounds__(256) void wconv_kernel(
    const float* __restrict__ Wq, const float* __restrict__ Wk, const float* __restrict__ Wv,
    const float* __restrict__ Wp,
    unsigned short* __restrict__ Wt3, unsigned short* __restrict__ Wpt)
{
    __shared__ unsigned short tile[64 * 64];
    const int t = threadIdx.x;
    const int bid = blockIdx.x;

    const float* src;
    unsigned short* dst;
    int src_ld, dst_ld;
    if (bid < 12) {
        const int m = bid >> 2, h = bid & 3;
        const float* W = (m == 0) ? Wq : ((m == 1) ? Wk : Wv);
        src = W + (h << 12);            // [d][e], ld 64
        dst = Wt3 + (m << 14) + (h << 12);  // [e][d], ld 64
        src_ld = 64; dst_ld = 64;
    } else {
        const int b2 = bid - 12;
        const int er = b2 >> 2, cr = b2 & 3;
        src = Wp + (size_t)(cr * 64) * OUTv + er * 64;   // rows c, cols e; ld 256
        dst = Wpt + (size_t)(er * 64) * HD + cr * 64;    // rows e, cols c; ld 256
        src_ld = OUTv; dst_ld = HD;
    }

    // load: thread -> src row r = t>>2, 16 cols at (t&3)*16
    {
        const int r = t >> 2, c0 = (t & 3) * 16;
        const float* s = src + (size_t)r * src_ld + c0;
        float f[16];
        *(float4*)(f)      = *(const float4*)(s);
        *(float4*)(f + 4)  = *(const float4*)(s + 4);
        *(float4*)(f + 8)  = *(const float4*)(s + 8);
        *(float4*)(f + 12) = *(const float4*)(s + 12);
#pragma unroll
        for (int i = 0; i < 16; ++i)
            tile[r * 64 + ((c0 + i + r) & 63)] = f2bf(f[i]);
    }
    __syncthreads();
    // write transposed: thread -> dst row e = t>>2, 16 d at (t&3)*16
    {
        const int e = t >> 2, d0 = (t & 3) * 16;
        unsigned v[8];
#pragma unroll
        for (int p = 0; p < 8; ++p) {
            const int da = d0 + 2 * p, db = da + 1;
            const unsigned lo = tile[da * 64 + ((e + da) & 63)];
            const unsigned hi = tile[db * 64 + ((e + db) & 63)];
            v[p] = lo | (hi << 16);
        }
        uint4* d16 = (uint4*)(dst + (size_t)e * dst_ld + d0);
        uint4 o0; o0.x = v[0]; o0.y = v[1]; o0.z = v[2]; o0.w = v[3];
        uint4 o1; o1.x = v[4]; o1.y = v[5]; o1.z = v[6]; o1.w = v[7];
        d16[0] = o0; d16[1] = o1;
    }
}

// ---------------------------------------------------------------------------
// Kernel 1: QKV projection MFMA GEMM, M-tile 128 (512 blocks, 2/CU).
// X packed in-kernel (fp32->bf16), W staged bf16 via global_load_lds.
// Merged single-phase epilogue. Q,K -> [bh][n][d]; V -> [bh][d][n].
// Q pre-scaled by (1/8)*log2(e).
// ---------------------------------------------------------------------------
__global__ __launch_bounds__(256) void qkv_kernel(
    const float* __restrict__ x,
    const unsigned short* __restrict__ Wt3,
    const float* __restrict__ bq, const float* __restrict__ bk, const float* __restrict__ bv,
    unsigned short* __restrict__ Qb, unsigned short* __restrict__ Kb,
    unsigned short* __restrict__ Vt)
{
    const int h = blockIdx.x & 3;
    const int tt = blockIdx.x >> 2;          // 0..127
    const int tok0 = tt * 128;
    const int t = threadIdx.x, l = t & 63, w = t >> 6;
    const int lg = l >> 4, lc = l & 15;

    __shared__ uint4 Xs[128 * 8];       // 16 KB [tok][d-chunk^]; reused as K repack
    __shared__ uint4 Ws[3 * 512];       // 24 KB [m][e][d-chunk^]; reused as V repack
    __shared__ uint4 Os[128 * 8];       // 16 KB Q repack

    // ---- stage W (bf16, pre-transposed): 1536 slots, 6/thread (issue first)
#pragma unroll
    for (int k = 0; k < 6; ++k) {
        const int s = k * 256 + t;
        const int m = s >> 9, sm = s & 511;
        const int e = sm >> 3, cp = sm & 7;
        __builtin_amdgcn_global_load_lds(
            (const GLOBAL_AS unsigned int*)(Wt3 + (m << 14) + (h << 12) + (e << 6) + ((cp ^ (e & 7)) << 3)),
            (LDS_AS unsigned int*)((char*)Ws + (k * 256 + w * 64) * 16),
            16, 0, 0);
    }

    // ---- stage x tile -> bf16 via VALU pack (overlaps W DMA): 32 floats/thread
    {
        const int r = t >> 1, hf = t & 1;
        const float* src = x + (size_t)(tok0 + r) * HD + h * Dv + hf * 32;
        float f[32];
#pragma unroll
        for (int p = 0; p < 8; ++p)
            *(float4*)(f + p * 4) = *(const float4*)(src + p * 4);
#pragma unroll
        for (int p = 0; p < 4; ++p)
            Xs[r * 8 + ((hf * 4 + p) ^ (r & 7))] = pack8(f + p * 8);
    }
    asm volatile("s_waitcnt vmcnt(0)" ::: "memory");
    __syncthreads();

    // ---- fragments: wave w owns rows w*32..w*32+31 (2 row-groups)
    bf16x8 a[2][2];
#pragma unroll
    for (int rg = 0; rg < 2; ++rg) {
        const int ar = w * 32 + rg * 16 + lc;
        a[rg][0] = ((const bf16x8*)Xs)[ar * 8 + (lg       ^ (ar & 7))];
        a[rg][1] = ((const bf16x8*)Xs)[ar * 8 + ((4 + lg) ^ (ar & 7))];
    }

    f32x4 acc[3][2][4];
#pragma unroll
    for (int m = 0; m < 3; ++m)
#pragma unroll
        for (int rg = 0; rg < 2; ++rg)
#pragma unroll
            for (int nt = 0; nt < 4; ++nt) acc[m][rg][nt] = (f32x4){0.f, 0.f, 0.f, 0.f};

#pragma unroll
    for (int kk = 0; kk < 2; ++kk) {
#pragma unroll
        for (int m = 0; m < 3; ++m) {
#pragma unroll
            for (int nt = 0; nt < 4; ++nt) {
                const int br = nt * 16 + lc;
                const bf16x8 b = ((const bf16x8*)Ws)[(m << 9) + br * 8 + ((kk * 4 + lg) ^ (br & 7))];
#pragma unroll
                for (int rg = 0; rg < 2; ++rg)
                    acc[m][rg][nt] = __builtin_amdgcn_mfma_f32_16x16x32_bf16(a[rg][kk], b, acc[m][rg][nt], 0, 0, 0);
            }
        }
    }

    const int b_ = tok0 >> 11, n_ = tok0 & (Nv - 1);
    const int bh = b_ * Hv + h;
    const float QSCALE = 0.125f * 1.44269504088896340736f;  // 1/sqrt(64)*log2(e)

    __syncthreads();   // Xs/Ws fragment reads done in all waves
    {
        unsigned short* Os16 = (unsigned short*)Os;
        unsigned short* Ks16 = (unsigned short*)Xs;
        unsigned short* Vs16 = (unsigned short*)Ws;
#pragma unroll
        for (int nt = 0; nt < 4; ++nt) {
            const int e = nt * 16 + lc;
            const float bq_ = bq[h * Dv + e];
            const float bk_ = bk[h * Dv + e];
            const float bv_ = bv[h * Dv + e];
#pragma unroll
            for (int rg = 0; rg < 2; ++rg) {
#pragma unroll
                for (int j = 0; j < 4; ++j) {
                    const int row = w * 32 + rg * 16 + lg * 4 + j;   // token 0..127
                    const int ch = (e >> 3) ^ (row & 7);
                    Os16[row * 64 + ch * 8 + (e & 7)] = f2bf((acc[0][rg][nt][j] + bq_) * QSCALE);
                    Ks16[row * 64 + ch * 8 + (e & 7)] = f2bf(acc[1][rg][nt][j] + bk_);
                    const int cv = row >> 3;                          // 0..15
                    const int pv = ((cv ^ e) & 7) | (cv & 8);
                    Vs16[e * 128 + pv * 8 + (row & 7)] = f2bf(acc[2][rg][nt][j] + bv_);
                }
            }
        }
    }
    __syncthreads();
    {
        // Q,K stores: 2 threads/row, 4 chunks each
        const int r = t >> 1, cq = (t & 1) * 4;
        unsigned short* dq = Qb + ((size_t)bh * Nv + n_ + r) * Dv;
        unsigned short* dk = Kb + ((size_t)bh * Nv + n_ + r) * Dv;
#pragma unroll
        for (int i = 0; i < 4; ++i) {
            const int ch = cq + i;
            *(uint4*)(dq + ch * 8) = Os[r * 8 + (ch ^ (r & 7))];
            *(uint4*)(dk + ch * 8) = Xs[r * 8 + (ch ^ (r & 7))];
        }
        // V stores: 4 threads/row (e), 4 chunks each
        const int e = t >> 2, cv0 = (t & 3) * 4;
        unsigned short* dv = Vt + ((size_t)bh * Dv + e) * Nv + n_;
#pragma unroll
        for (int i = 0; i < 4; ++i) {
            const int c = cv0 + i;
            const int pv = ((c ^ e) & 7) | (c & 8);
            *(uint4*)(dv + c * 8) = Ws[e * 16 + pv];
        }
    }
}

// ---------------------------------------------------------------------------
// Kernel 2: flash attention (round-8 structure, measured 52.8 us — unchanged).
// ---------------------------------------------------------------------------
__global__ __launch_bounds__(256, 2) void attn_kernel(
    const unsigned short* __restrict__ Qb, const unsigned short* __restrict__ Kb,
    const unsigned short* __restrict__ Vt, unsigned short* __restrict__ Ob)
{
    const int bh = blockIdx.x & 31;
    const int qt = blockIdx.x >> 5;
    const int t = threadIdx.x, w = t >> 6, l = t & 63;
    const int hi = l >> 5, lc = l & 31;

    __shared__ uint4 Ks[2][128 * 8];   // 16 KB each: [kv][d-chunk^]
    __shared__ uint4 Vs[2][64 * 16];   // 16 KB each: [d][kv-chunk^]

    const unsigned short* Kg = Kb + (size_t)bh * Nv * Dv;
    const unsigned short* Vg = Vt + (size_t)bh * Dv * Nv;

    const int q_ = qt * 128 + w * 32 + lc;
    const unsigned short* Qrow = Qb + ((size_t)bh * Nv + q_) * Dv;
    bf16x8 qf[4];
#pragma unroll
    for (int kk = 0; kk < 4; ++kk)
        qf[kk] = *(const bf16x8*)(Qrow + kk * 16 + hi * 8);

    bf16x8 onesf;
#pragma unroll
    for (int i = 0; i < 8; ++i) onesf[i] = (__bf16)1.0f;

    auto stage = [&](int buf, int kt) {
#pragma unroll
        for (int k = 0; k < 4; ++k) {
            const int s = k * 256 + t;
            const int base = k * 256 + w * 64;
            {
                const int r = s >> 3, c = (s & 7) ^ (r & 7);
                __builtin_amdgcn_global_load_lds(
                    (const GLOBAL_AS unsigned int*)(Kg + ((size_t)kt * 128 + r) * Dv + c * 8),
                    (LDS_AS unsigned int*)((char*)&Ks[buf][0] + base * 16),
                    16, 0, 0);
            }
            {
                const int r = s >> 4, c = (s & 15) ^ (r & 15);
                __builtin_amdgcn_global_load_lds(
                    (const GLOBAL_AS unsigned int*)(Vg + (size_t)r * Nv + kt * 128 + c * 8),
                    (LDS_AS unsigned int*)((char*)&Vs[buf][0] + base * 16),
                    16, 0, 0);
            }
        }
    };

    f32x16 o0, o1, o2, z16;
#pragma unroll
    for (int i = 0; i < 16; ++i) { o0[i] = 0.f; o1[i] = 0.f; o2[i] = 0.f; z16[i] = 0.f; }

    stage(0, 0);
    asm volatile("s_waitcnt vmcnt(0)" ::: "memory");
    __syncthreads();

    int cur = 0;
    for (int kt = 0; kt < Nv / 128; ++kt) {
        if (kt < Nv / 128 - 1) stage(cur ^ 1, kt + 1);

        const uint4* KsB = &Ks[cur][0];
        const uint4* VsB = &Vs[cur][0];

        f32x16 s4[4];
        __builtin_amdgcn_s_setprio(1);
#pragma unroll
        for (int nt = 0; nt < 4; ++nt) {
            const int r = nt * 32 + lc;
            const bf16x8 af = *(const bf16x8*)&KsB[r * 8 + (hi ^ (r & 7))];
            s4[nt] = __builtin_amdgcn_mfma_f32_32x32x16_bf16(af, qf[0], z16, 0, 0, 0);
        }
#pragma unroll
        for (int kk = 1; kk < 4; ++kk) {
#pragma unroll
            for (int nt = 0; nt < 4; ++nt) {
                const int r = nt * 32 + lc;
                const bf16x8 af = *(const bf16x8*)&KsB[r * 8 + ((kk * 2 + hi) ^ (r & 7))];
                s4[nt] = __builtin_amdgcn_mfma_f32_32x32x16_bf16(af, qf[kk], s4[nt], 0, 0, 0);
            }
        }
        __builtin_amdgcn_s_setprio(0);

#pragma unroll
        for (int nt = 0; nt < 4; ++nt) {
#pragma unroll
            for (int r = 0; r < 16; ++r) s4[nt][r] = EXP2(s4[nt][r]);

            unsigned c[8];
#pragma unroll
            for (int i = 0; i < 8; ++i) c[i] = pk_bf16(s4[nt][2 * i], s4[nt][2 * i + 1]);

            unsigned d0a, d2a, d1a, d3a, d0b, d2b, d1b, d3b;
            swap32(c[0], c[2], d0a, d2a);
            swap32(c[1], c[3], d1a, d3a);
            swap32(c[4], c[6], d0b, d2b);
            swap32(c[5], c[7], d1b, d3b);

            union { unsigned u[4]; bf16x8 v; } pf0, pf1;
            pf0.u[0] = d0a; pf0.u[1] = d1a; pf0.u[2] = d2a; pf0.u[3] = d3a;
            pf1.u[0] = d0b; pf1.u[1] = d1b; pf1.u[2] = d2b; pf1.u[3] = d3b;

            __builtin_amdgcn_s_setprio(1);
#pragma unroll
            for (int kslow = 0; kslow < 2; ++kslow) {
                const bf16x8 pf = kslow ? pf1.v : pf0.v;
                {
                    const int row = lc;
                    const int ch = (nt * 4 + kslow * 2 + hi) ^ (row & 15);
                    const bf16x8 vf = *(const bf16x8*)&VsB[row * 16 + ch];
                    o0 = __builtin_amdgcn_mfma_f32_32x32x16_bf16(vf, pf, o0, 0, 0, 0);
                }
                {
                    const int row = 32 + lc;
                    const int ch = (nt * 4 + kslow * 2 + hi) ^ (row & 15);
                    const bf16x8 vf = *(const bf16x8*)&VsB[row * 16 + ch];
                    o1 = __builtin_amdgcn_mfma_f32_32x32x16_bf16(vf, pf, o1, 0, 0, 0);
                }
                o2 = __builtin_amdgcn_mfma_f32_32x32x16_bf16(onesf, pf, o2, 0, 0, 0);
            }
            __builtin_amdgcn_s_setprio(0);
        }

        if (kt < Nv / 128 - 1) {
            asm volatile("s_waitcnt vmcnt(0)" ::: "memory");
            __syncthreads();
            cur ^= 1;
        }
    }

    const float inv = 1.0f / o2[0];
    const int b_ = bh >> 2, h_ = bh & 3;
    unsigned short* orow = Ob + ((size_t)b_ * Nv + q_) * HD + h_ * Dv;
#pragma unroll
    for (int g = 0; g < 4; ++g) {
        uint2 ua, ub;
        ua.x = pk_bf16(o0[g * 4 + 0] * inv, o0[g * 4 + 1] * inv);
        ua.y = pk_bf16(o0[g * 4 + 2] * inv, o0[g * 4 + 3] * inv);
        ub.x = pk_bf16(o1[g * 4 + 0] * inv, o1[g * 4 + 1] * inv);
        ub.y = pk_bf16(o1[g * 4 + 2] * inv, o1[g * 4 + 3] * inv);
        *(uint2*)(orow + 8 * g + 4 * hi)      = ua;
        *(uint2*)(orow + 32 + 8 * g + 4 * hi) = ub;
    }
}

// ---------------------------------------------------------------------------
// Kernel 3: output projection MFMA GEMM. M-tile 64 (256 blocks, 1/CU),
// double-buffered k-loop with counted vmcnt(10). 80 KB LDS.
// ---------------------------------------------------------------------------
__global__ __launch_bounds__(256) void proj_kernel(
    const unsigned short* __restrict__ Ob, const unsigned short* __restrict__ Wpt,
    const float* __restrict__ bp, float* __restrict__ out)
{
    const int tok0 = blockIdx.x * 64;
    const int t = threadIdx.x, w = t >> 6, l = t & 63;
    const int hi = l >> 5, lc = l & 31;
    const int tw = w >> 1;

    __shared__ uint4 SH[2][2560];   // 80 KB: per buf [0,512) O-tile, [512,2560) W-slice

    auto stage = [&](int buf, int kt) {
        const int c0 = kt * 64;
#pragma unroll
        for (int j = 0; j < 10; ++j) {
            const int s = j * 256 + t;
            const int base = j * 256 + w * 64;
            if (s < 512) {
                const int r = s >> 3, cp = s & 7;
                __builtin_amdgcn_global_load_lds(
                    (const GLOBAL_AS unsigned int*)(Ob + (size_t)(tok0 + r) * HD + c0 + ((cp ^ (r & 7)) << 3)),
                    (LDS_AS unsigned int*)((char*)&SH[buf][0] + base * 16),
                    16, 0, 0);
            } else {
                const int s2 = s - 512;
                const int e = s2 >> 3, cp = s2 & 7;
                __builtin_amdgcn_global_load_lds(
                    (const GLOBAL_AS unsigned int*)(Wpt + (size_t)e * HD + c0 + ((cp ^ (e & 7)) << 3)),
                    (LDS_AS unsigned int*)((char*)&SH[buf][0] + base * 16),
                    16, 0, 0);
            }
        }
    };

    f32x16 acc[4];
#pragma unroll
    for (int ct = 0; ct < 4; ++ct)
#pragma unroll
        for (int i = 0; i < 16; ++i) acc[ct][i] = 0.f;

    stage(0, 0);
    for (int kt = 0; kt < 4; ++kt) {
        if (kt < 3) {
            stage((kt + 1) & 1, kt + 1);
            asm volatile("s_waitcnt vmcnt(10)" ::: "memory");   // stage(kt) landed
        } else {
            asm volatile("s_waitcnt vmcnt(0)" ::: "memory");
        }
        __syncthreads();

        const bf16x8* Osh = (const bf16x8*)&SH[kt & 1][0];
        const bf16x8* Wsh = (const bf16x8*)&SH[kt & 1][512];
        const int r = tw * 32 + lc;
#pragma unroll
        for (int kk = 0; kk < 4; ++kk) {
            const bf16x8 af = Osh[r * 8 + ((kk * 2 + hi) ^ (r & 7))];
#pragma unroll
            for (int ct = 0; ct < 4; ++ct) {
                const int e = (w & 1) * 128 + ct * 32 + lc;
                const bf16x8 bf_ = Wsh[e * 8 + ((kk * 2 + hi) ^ (e & 7))];
                acc[ct] = __builtin_amdgcn_mfma_f32_32x32x16_bf16(af, bf_, acc[ct], 0, 0, 0);
            }
        }
        __syncthreads();   // buf free for stage(kt+2)
    }

#pragma unroll
    for (int ct = 0; ct < 4; ++ct) {
        const int e = (w & 1) * 128 + ct * 32 + lc;
        const float bias = bp[e];
#pragma unroll
        for (int r = 0; r < 16; ++r) {
            const int tok = tok0 + tw * 32 + (r & 3) + 8 * (r >> 2) + 4 * hi;
            out[(size_t)tok * OUTv + e] = acc[ct][r] + bias;
        }
    }
}

// ---------------------------------------------------------------------------
extern "C" void kernel_launch(void* const* d_in, const int* in_sizes, int n_in,
                              void* d_out, int out_size, void* d_ws, size_t ws_size,
                              hipStream_t stream)
{
    const float* x  = (const float*)d_in[0];
    const float* Wq = (const float*)d_in[1];
    const float* Wk = (const float*)d_in[2];
    const float* Wv = (const float*)d_in[3];
    const float* bq = (const float*)d_in[4];
    const float* bk = (const float*)d_in[5];
    const float* bv = (const float*)d_in[6];
    const float* Wp = (const float*)d_in[7];
    const float* bp = (const float*)d_in[8];
    float* out = (float*)d_out;

    unsigned short* us = (unsigned short*)d_ws;
    unsigned short* Qb  = us;
    unsigned short* Kb  = us + PH;
    unsigned short* Vt  = us + 2 * PH;
    unsigned short* Ob  = us + 3 * PH;
    unsigned short* Wt3 = us + 4 * PH;
    unsigned short* Wpt = Wt3 + 49152;

    wconv_kernel<<<28, 256, 0, stream>>>(Wq, Wk, Wv, Wp, Wt3, Wpt);
    qkv_kernel<<<(Bv * Nv / 128) * Hv, 256, 0, stream>>>(x, Wt3, bq, bk, bv, Qb, Kb, Vt);
    attn_kernel<<<(Nv / 128) * BH, 256, 0, stream>>>(Qb, Kb, Vt, Ob);
    proj_kernel<<<Bv * Nv / 64, 256, 0, stream>>>(Ob, Wpt, bp, out);
}